// Round 6
// baseline (1785.666 us; speedup 1.0000x reference)
//
#include <hip/hip_runtime.h>
#include <hip/hip_bf16.h>

// ModernNCA fused pipeline for MI355X (gfx950). Round 6: occupancy + epilogue.
//
// R5 lesson: MFMA-logits killed the atomic floor (763->328us) but dist is
// still latency-bound at 1 block/CU (101KB LDS, 8 waves). R6: LDS to exactly
// 80KB -> 2 blocks/CU (16 waves, 4/SIMD); VGPR <=128 via per-tile sumexp
// flush (no persistent sume regs); ed scratch XOR-swizzled (8-way -> 4-way
// conflicts on logit A-frag reads); 8-deep b-ring without wrap reloads.
//
// Padding: 5000->5120 per chunk; pad rows c=0, csq=1e4 -> d>=100 -> ed==0;
// each pad adds exp(0)=1 to chunk sumexp; finalize subtracts 120.

typedef _Float16 f16x8 __attribute__((ext_vector_type(8)));
typedef _Float16 f16x4 __attribute__((ext_vector_type(4)));
typedef float f32x4 __attribute__((ext_vector_type(4)));
typedef float f32x16 __attribute__((ext_vector_type(16)));

#define MFMA16(a, b, c) __builtin_amdgcn_mfma_f32_16x16x32_f16(a, b, c, 0, 0, 0)
#define MFMA32(a, b, c) __builtin_amdgcn_mfma_f32_32x32x16_f16(a, b, c, 0, 0, 0)

// ---------------- prep: W1t/W2t transpose+cast, padded y, zero accumulators
__global__ __launch_bounds__(256) void prep_kernel(
    const float* __restrict__ W1, const float* __restrict__ W2,
    const int* __restrict__ y, _Float16* __restrict__ w1t,
    _Float16* __restrict__ w2t, int* __restrict__ ypad,
    float* __restrict__ zero_base) {
  int idx = blockIdx.x * 256 + threadIdx.x;
  if (idx < 49152) {                       // W1 [96,512] -> W1t [512,96]
    int n = idx / 96, k = idx - n * 96;
    w1t[idx] = (_Float16)W1[k * 512 + n];
  } else if (idx < 311296) {               // W2 [512,512] -> W2t [512,512]
    int j = idx - 49152;
    int n = j / 512, k = j - n * 512;
    w2t[j] = (_Float16)W2[k * 512 + n];
  } else if (idx < 413696) {               // padded candidate_y
    int j = idx - 311296;
    int ch = j / 5120, pos = j - ch * 5120;
    ypad[j] = (pos < 5000) ? y[ch * 5000 + pos] : 0;
  } else if (idx < 619520) {
    // zero: csq(102400) qsq(1024) sumexp(20480) lgts_part(81920) = 205824 f32
    zero_base[idx - 413696] = 0.0f;
  }
}

// ---------------- fused 2-layer encoder: enc = relu(x@W1+b1)@W2 + b2
// (unchanged from R5 — will revisit once dist is no longer the top dispatch)
template <int CHUNK_IN, int CHUNK_OUT>
__global__ __launch_bounds__(256, 2) void encode_kernel(
    const float* __restrict__ xn, const float* __restrict__ xc,
    const _Float16* __restrict__ w1t, const float* __restrict__ b1,
    const _Float16* __restrict__ w2t, const float* __restrict__ b2,
    _Float16* __restrict__ out, float* __restrict__ outsq) {
  __shared__ __align__(16) char lds_x[16384];  // 64 rows x 16 units(16B) swz
  __shared__ __align__(16) char lds_h[65536];  // 64 rows x 64 units(16B) swz

  const int t = threadIdx.x;
  const int R0 = blockIdx.x * 64;
  const int w = t >> 6, l = t & 63;
  const int l15 = l & 15, quad = l >> 4;
  const int ncol0 = w * 128;

#pragma unroll
  for (int it = 0; it < 4; it++) {
    int idx = it * 256 + t;
    int row = idx >> 4, kq = idx & 15;
    int pr = R0 + row;
    int ch = pr / CHUNK_OUT, pos = pr - ch * CHUNK_OUT;
    float v[8] = {0, 0, 0, 0, 0, 0, 0, 0};
    if (pos < CHUNK_IN && kq < 12) {
      int orig = ch * CHUNK_IN + pos;
      float4 f0, f1;
      if (kq < 8) {
        f0 = *(const float4*)&xn[orig * 64 + kq * 8];
        f1 = *(const float4*)&xn[orig * 64 + kq * 8 + 4];
      } else {
        f0 = *(const float4*)&xc[orig * 32 + (kq - 8) * 8];
        f1 = *(const float4*)&xc[orig * 32 + (kq - 8) * 8 + 4];
      }
      v[0] = f0.x; v[1] = f0.y; v[2] = f0.z; v[3] = f0.w;
      v[4] = f1.x; v[5] = f1.y; v[6] = f1.z; v[7] = f1.w;
    }
    f16x8 hv;
#pragma unroll
    for (int j = 0; j < 8; j++) hv[j] = (_Float16)v[j];
    *(f16x8*)&lds_x[row * 256 + (((kq ^ (row & 7)) & 15) << 4)] = hv;
  }
  __syncthreads();

  f32x4 acc1[8][4];
#pragma unroll
  for (int ni = 0; ni < 8; ni++)
#pragma unroll
    for (int rt = 0; rt < 4; rt++) acc1[ni][rt] = (f32x4)(0.0f);

#pragma unroll
  for (int kt = 0; kt < 3; kt++) {
    f16x8 bx[4];
#pragma unroll
    for (int rt = 0; rt < 4; rt++) {
      int row = rt * 16 + l15;
      int kq = kt * 4 + quad;
      bx[rt] = *(const f16x8*)&lds_x[row * 256 + (((kq ^ (row & 7)) & 15) << 4)];
    }
#pragma unroll
    for (int ni = 0; ni < 8; ni++) {
      f16x8 aw = *(const f16x8*)&w1t[(ncol0 + ni * 16 + l15) * 96 + kt * 32 + quad * 8];
#pragma unroll
      for (int rt = 0; rt < 4; rt++) acc1[ni][rt] = MFMA16(aw, bx[rt], acc1[ni][rt]);
    }
  }

#pragma unroll
  for (int ni = 0; ni < 8; ni++) {
    float4 b1v = *(const float4*)&b1[ncol0 + ni * 16 + quad * 4];
    int kq2 = (ncol0 >> 3) + ni * 2 + (quad >> 1);
#pragma unroll
    for (int rt = 0; rt < 4; rt++) {
      int row = rt * 16 + l15;
      f16x4 hv;
      hv[0] = (_Float16)fmaxf(acc1[ni][rt][0] + b1v.x, 0.0f);
      hv[1] = (_Float16)fmaxf(acc1[ni][rt][1] + b1v.y, 0.0f);
      hv[2] = (_Float16)fmaxf(acc1[ni][rt][2] + b1v.z, 0.0f);
      hv[3] = (_Float16)fmaxf(acc1[ni][rt][3] + b1v.w, 0.0f);
      int swz = (kq2 & ~7) | ((kq2 & 7) ^ (row & 7));
      *(f16x4*)&lds_h[row * 1024 + (swz << 4) + ((quad & 1) << 3)] = hv;
    }
  }
  __syncthreads();

  f32x4 acc2[8][4];
#pragma unroll
  for (int ni = 0; ni < 8; ni++)
#pragma unroll
    for (int rt = 0; rt < 4; rt++) acc2[ni][rt] = (f32x4)(0.0f);

#pragma unroll 2
  for (int kt = 0; kt < 16; kt++) {
    f16x8 bh[4];
#pragma unroll
    for (int rt = 0; rt < 4; rt++) {
      int row = rt * 16 + l15;
      int kq = kt * 4 + quad;
      int swz = (kq & ~7) | ((kq & 7) ^ (row & 7));
      bh[rt] = *(const f16x8*)&lds_h[row * 1024 + (swz << 4)];
    }
#pragma unroll
    for (int ni = 0; ni < 8; ni++) {
      f16x8 aw = *(const f16x8*)&w2t[(ncol0 + ni * 16 + l15) * 512 + kt * 32 + quad * 8];
#pragma unroll
      for (int rt = 0; rt < 4; rt++)
        acc2[ni][rt] = MFMA16(aw, bh[rt], acc2[ni][rt]);
    }
  }

#pragma unroll
  for (int rt = 0; rt < 4; rt++) {
    int pr = R0 + rt * 16 + l15;
    int ch = pr / CHUNK_OUT, pos = pr - ch * CHUNK_OUT;
    bool valid = pos < CHUNK_IN;
    float s = 0.0f;
#pragma unroll
    for (int ni = 0; ni < 8; ni++) {
      float4 b2v = *(const float4*)&b2[ncol0 + ni * 16 + quad * 4];
      f16x4 ov;
      if (valid) {
        ov[0] = (_Float16)(acc2[ni][rt][0] + b2v.x);
        ov[1] = (_Float16)(acc2[ni][rt][1] + b2v.y);
        ov[2] = (_Float16)(acc2[ni][rt][2] + b2v.z);
        ov[3] = (_Float16)(acc2[ni][rt][3] + b2v.w);
#pragma unroll
        for (int r = 0; r < 4; r++) {
          float cv = (float)ov[r];
          s += cv * cv;
        }
      } else {
        ov[0] = (_Float16)0.0f; ov[1] = (_Float16)0.0f;
        ov[2] = (_Float16)0.0f; ov[3] = (_Float16)0.0f;
        s += 4.0f * 19.53125f;               // 1e4 / 512 per pad element
      }
      *(f16x4*)&out[pr * 512 + ncol0 + ni * 16 + quad * 4] = ov;
    }
    s += __shfl_xor(s, 16);
    s += __shfl_xor(s, 32);
    if (quad == 0) atomicAdd(&outsq[pr], s);
  }
}

// ---------------- fused distance + reductions
// 1280 blocks x 512 threads, LDS exactly 80KB -> 2 blocks/CU (16 waves).
// id: xcd=id&7 (owns cols [xcd*12800,+12800)), by=(id>>3)&15 (64 q-rows),
// m=id>>7 -> col-group g=xcd*10+m (1280 cols; wave w does tiles w,w+8,..).
// Per 64x32 tile: 8-deep b-ring streams c global->VGPR; epilogue in two
// 32-row half-passes through a wave-private swizzled 2KB ed scratch feeding
// the one-hot logit MFMA; sumexp shuffle-reduced + flushed per tile.
__global__ __launch_bounds__(512, 4) void dist_kernel(
    const _Float16* __restrict__ q, const _Float16* __restrict__ c,
    const float* __restrict__ qsq, const float* __restrict__ csq,
    const int* __restrict__ ypad, float* __restrict__ sumexp,
    float* __restrict__ lgts_part) {
  __shared__ __align__(16) char lds_q[65536];   // 64 rows x 64 units(16B) swz
  __shared__ __align__(16) char lds_ed[16384];  // 8 waves x 2KB (32x32 f16 swz)

  const int t = threadIdx.x, w = t >> 6, l = t & 63;
  const int l31 = l & 31, half = l >> 5;
  const int l15 = l & 15, quad = (l >> 4) & 3;
  const int id = blockIdx.x;
  const int xcd = id & 7, by = (id >> 3) & 15, m = id >> 7;
  const int g = xcd * 10 + m;
  const int row0 = by * 64, chunk = g >> 2;   // 4 col-groups per 5120-chunk

  // stage q rows [row0, row0+64) into swizzled LDS (coalesced, one-time)
#pragma unroll
  for (int it = 0; it < 8; it++) {
    int idx = it * 512 + t;
    int row = idx >> 6, u = idx & 63;
    f16x8 v = *(const f16x8*)&q[(size_t)(row0 + row) * 512 + u * 8];
    int swz = (u & ~7) | ((u & 7) ^ (row & 7));
    *(f16x8*)&lds_q[row * 1024 + (swz << 4)] = v;
  }
  __syncthreads();

  f32x4 lacc[4];
#pragma unroll
  for (int i = 0; i < 4; i++) lacc[i] = (f32x4)(0.0f);

  char* edbase = lds_ed + w * 2048;   // wave-private 32x32 f16 scratch (swz)

  for (int tile = w; tile < 40; tile += 8) {
    int col0 = g * 1280 + tile * 32;
    const _Float16* cb = c + (size_t)(col0 + l31) * 512 + half * 8;

    f32x16 acc[2];
    acc[0] = (f32x16)(0.0f);
    acc[1] = (f32x16)(0.0f);

    f16x8 br[8];
#pragma unroll
    for (int i = 0; i < 8; i++) br[i] = *(const f16x8*)(cb + i * 16);

#pragma unroll
    for (int ks = 0; ks < 32; ks++) {
      f16x8 bc = br[ks & 7];
      if (ks < 24) br[ks & 7] = *(const f16x8*)(cb + (ks + 8) * 16);
      int u = ks * 2 + half;
      int swz = (u & ~7) | ((u & 7) ^ (l31 & 7));   // (32+l31)&7 == l31&7
      f16x8 a0 = *(const f16x8*)&lds_q[l31 * 1024 + (swz << 4)];
      f16x8 a1 = *(const f16x8*)&lds_q[(32 + l31) * 1024 + (swz << 4)];
      acc[0] = MFMA32(a0, bc, acc[0]);
      acc[1] = MFMA32(a1, bc, acc[1]);
    }

    // one-hot B-frag from ypad (classes in [0,10) -> lanes l15>=10 get zeros)
    int4 ya = *(const int4*)&ypad[col0 + quad * 8];
    int4 yb = *(const int4*)&ypad[col0 + quad * 8 + 4];
    f16x8 bf;
    bf[0] = (_Float16)(ya.x == l15 ? 1.0f : 0.0f);
    bf[1] = (_Float16)(ya.y == l15 ? 1.0f : 0.0f);
    bf[2] = (_Float16)(ya.z == l15 ? 1.0f : 0.0f);
    bf[3] = (_Float16)(ya.w == l15 ? 1.0f : 0.0f);
    bf[4] = (_Float16)(yb.x == l15 ? 1.0f : 0.0f);
    bf[5] = (_Float16)(yb.y == l15 ? 1.0f : 0.0f);
    bf[6] = (_Float16)(yb.z == l15 ? 1.0f : 0.0f);
    bf[7] = (_Float16)(yb.w == l15 ? 1.0f : 0.0f);

    float cs = csq[col0 + l31];

    // two half-passes (rows 0-31 from acc[0], rows 32-63 from acc[1])
#pragma unroll
    for (int hp = 0; hp < 2; hp++) {
      f32x4 qsv[4];
#pragma unroll
      for (int j = 0; j < 4; j++)
        qsv[j] = *(const f32x4*)&qsq[row0 + hp * 32 + 4 * half + 8 * j];

#pragma unroll
      for (int reg = 0; reg < 16; reg++) {
        int rr = (reg & 3) + 8 * (reg >> 2) + 4 * half;   // local row 0..31
        float dd = qsv[reg >> 2][reg & 3] + cs - 2.0f * acc[hp][reg];
        float ed = __expf(-sqrtf(fmaxf(dd, 0.0f)));   // pad: d>=100 -> ed==0
        // ed -> swizzled scratch (same-wave DS ordering covers the read below)
        *(_Float16*)&edbase[rr * 64 + (((l31 >> 3) ^ (rr & 3)) << 4) +
                            (l31 & 7) * 2] = (_Float16)ed;
        // sumexp: exp(ed) reduced over the 32 col-lanes, 1 atomic per row
        float ev = __expf(ed);                         // pad adds exactly 1.0
        ev += __shfl_xor(ev, 1);
        ev += __shfl_xor(ev, 2);
        ev += __shfl_xor(ev, 4);
        ev += __shfl_xor(ev, 8);
        ev += __shfl_xor(ev, 16);
        if (l31 == 0)
          atomicAdd(&sumexp[(row0 + hp * 32 + rr) * 20 + chunk], ev);
      }

      // logits[row][class] += ed_half @ onehot
#pragma unroll
      for (int mt = 0; mt < 2; mt++) {
        int rowr = mt * 16 + l15;
        f16x8 af = *(const f16x8*)&edbase[rowr * 64 +
                                          ((quad ^ (rowr & 3)) << 4)];
        lacc[hp * 2 + mt] = MFMA16(af, bf, lacc[hp * 2 + mt]);
      }
    }
  }

  // flush logits straight to this XCD's partial array (C-layout: col=class)
  if (l15 < 10) {
    float* lp = lgts_part + (size_t)xcd * 10240 + row0 * 10;
#pragma unroll
    for (int i = 0; i < 4; i++) {
      int rbase = (i >> 1) * 32 + (i & 1) * 16 + quad * 4;
#pragma unroll
      for (int r = 0; r < 4; r++)
        atomicAdd(&lp[(rbase + r) * 10 + l15], lacc[i][r]);
    }
  }
}

// ---------------- finalize: out[i,k] = log(Σ_xcd lgts_part) - Σ_ch log(sumexp-120)
__global__ __launch_bounds__(256) void finalize_kernel(
    const float* __restrict__ lgts_part, const float* __restrict__ sumexp,
    float* __restrict__ out) {
  int i = blockIdx.x * 256 + threadIdx.x;
  if (i >= 1024) return;
  float lse = 0.0f;
#pragma unroll
  for (int ch = 0; ch < 20; ch++) lse += logf(sumexp[i * 20 + ch] - 120.0f);
#pragma unroll
  for (int k = 0; k < 10; k++) {
    float lg = 0.0f;
#pragma unroll
    for (int x = 0; x < 8; x++) lg += lgts_part[x * 10240 + i * 10 + k];
    out[i * 10 + k] = logf(lg) - lse;
  }
}

extern "C" void kernel_launch(void* const* d_in, const int* in_sizes, int n_in,
                              void* d_out, int out_size, void* d_ws, size_t ws_size,
                              hipStream_t stream) {
  const float* x_num = (const float*)d_in[0];
  const float* x_cat = (const float*)d_in[1];
  const float* cxn   = (const float*)d_in[2];
  const float* cxc   = (const float*)d_in[3];
  const int*   cy    = (const int*)d_in[4];
  const float* W1    = (const float*)d_in[5];
  const float* b1    = (const float*)d_in[6];
  const float* W2    = (const float*)d_in[7];
  const float* b2    = (const float*)d_in[8];
  float* out = (float*)d_out;

  char* ws = (char*)d_ws;
  _Float16* c    = (_Float16*)(ws + 0);           // 102400*512*2 = 104857600
  _Float16* qe   = (_Float16*)(ws + 104857600);   // 1024*512*2   = 1048576
  _Float16* w1t  = (_Float16*)(ws + 105906176);   // 512*96*2     = 98304
  _Float16* w2t  = (_Float16*)(ws + 106004480);   // 512*512*2    = 524288
  float*    csq  = (float*)(ws + 106528768);      // 102400*4     = 409600
  float*    qsq  = (float*)(ws + 106938368);      // 1024*4       = 4096
  float*    sume = (float*)(ws + 106942464);      // 1024*20*4    = 81920
  float*    lgtp = (float*)(ws + 107024384);      // 8*1024*10*4  = 327680
  int*      ypad = (int*)(ws + 107352064);        // 102400*4     = 409600

  prep_kernel<<<2420, 256, 0, stream>>>(W1, W2, cy, w1t, w2t, ypad, csq);
  encode_kernel<5000, 5120><<<1600, 256, 0, stream>>>(cxn, cxc, w1t, b1, w2t, b2, c, csq);
  encode_kernel<(1 << 20), (1 << 20)><<<16, 256, 0, stream>>>(x_num, x_cat, w1t, b1, w2t, b2, qe, qsq);
  dist_kernel<<<1280, 512, 0, stream>>>(qe, c, qsq, csq, ypad, sume, lgtp);
  finalize_kernel<<<4, 256, 0, stream>>>(lgtp, sume, out);
}

// Round 7
// 1015.652 us; speedup vs baseline: 1.7581x; 1.7581x over previous
//
#include <hip/hip_runtime.h>
#include <hip/hip_bf16.h>

// ModernNCA fused pipeline for MI355X (gfx950). Round 7.
//
// R6 lesson: launch_bounds(512,4) forced a 64-VGPR split -> K-loop spills
// (FETCH 2.5GB). Occupancy cannot be bought with these live ranges.
// R7 = R5 frame at (512,2) + in-wave cross-tile prefetch: the 8-deep b-ring
// refills with the NEXT tile's first 8 fragments during ks>=24, so next
// tile's L2 latency hides under this tile's VALU epilogue and the K-loop
// never starts cold. ed scratch swizzled with (row>>1)&3 (kills the 4-way
// read conflict); logit acc flushed straight to per-XCD global partials.
// encode: 1-deep software pipeline on the 8 w2t A-fragments.
//
// Padding: 5000->5120 per chunk; pad rows c=0, csq=1e4 -> d>=100 -> ed==0;
// each pad adds exp(0)=1 to chunk sumexp; finalize subtracts 120.

typedef _Float16 f16x8 __attribute__((ext_vector_type(8)));
typedef _Float16 f16x4 __attribute__((ext_vector_type(4)));
typedef float f32x4 __attribute__((ext_vector_type(4)));
typedef float f32x16 __attribute__((ext_vector_type(16)));

#define MFMA16(a, b, c) __builtin_amdgcn_mfma_f32_16x16x32_f16(a, b, c, 0, 0, 0)
#define MFMA32(a, b, c) __builtin_amdgcn_mfma_f32_32x32x16_f16(a, b, c, 0, 0, 0)

// ---------------- prep: W1t/W2t transpose+cast, padded y, zero accumulators
__global__ __launch_bounds__(256) void prep_kernel(
    const float* __restrict__ W1, const float* __restrict__ W2,
    const int* __restrict__ y, _Float16* __restrict__ w1t,
    _Float16* __restrict__ w2t, int* __restrict__ ypad,
    float* __restrict__ zero_base) {
  int idx = blockIdx.x * 256 + threadIdx.x;
  if (idx < 49152) {                       // W1 [96,512] -> W1t [512,96]
    int n = idx / 96, k = idx - n * 96;
    w1t[idx] = (_Float16)W1[k * 512 + n];
  } else if (idx < 311296) {               // W2 [512,512] -> W2t [512,512]
    int j = idx - 49152;
    int n = j / 512, k = j - n * 512;
    w2t[j] = (_Float16)W2[k * 512 + n];
  } else if (idx < 413696) {               // padded candidate_y
    int j = idx - 311296;
    int ch = j / 5120, pos = j - ch * 5120;
    ypad[j] = (pos < 5000) ? y[ch * 5000 + pos] : 0;
  } else if (idx < 619520) {
    // zero: csq(102400) qsq(1024) sumexp(20480) lgts_part(81920) = 205824 f32
    zero_base[idx - 413696] = 0.0f;
  }
}

// ---------------- fused 2-layer encoder: enc = relu(x@W1+b1)@W2 + b2
template <int CHUNK_IN, int CHUNK_OUT>
__global__ __launch_bounds__(256, 2) void encode_kernel(
    const float* __restrict__ xn, const float* __restrict__ xc,
    const _Float16* __restrict__ w1t, const float* __restrict__ b1,
    const _Float16* __restrict__ w2t, const float* __restrict__ b2,
    _Float16* __restrict__ out, float* __restrict__ outsq) {
  __shared__ __align__(16) char lds_x[16384];  // 64 rows x 16 units(16B) swz
  __shared__ __align__(16) char lds_h[65536];  // 64 rows x 64 units(16B) swz

  const int t = threadIdx.x;
  const int R0 = blockIdx.x * 64;
  const int w = t >> 6, l = t & 63;
  const int l15 = l & 15, quad = l >> 4;
  const int ncol0 = w * 128;

#pragma unroll
  for (int it = 0; it < 4; it++) {
    int idx = it * 256 + t;
    int row = idx >> 4, kq = idx & 15;
    int pr = R0 + row;
    int ch = pr / CHUNK_OUT, pos = pr - ch * CHUNK_OUT;
    float v[8] = {0, 0, 0, 0, 0, 0, 0, 0};
    if (pos < CHUNK_IN && kq < 12) {
      int orig = ch * CHUNK_IN + pos;
      float4 f0, f1;
      if (kq < 8) {
        f0 = *(const float4*)&xn[orig * 64 + kq * 8];
        f1 = *(const float4*)&xn[orig * 64 + kq * 8 + 4];
      } else {
        f0 = *(const float4*)&xc[orig * 32 + (kq - 8) * 8];
        f1 = *(const float4*)&xc[orig * 32 + (kq - 8) * 8 + 4];
      }
      v[0] = f0.x; v[1] = f0.y; v[2] = f0.z; v[3] = f0.w;
      v[4] = f1.x; v[5] = f1.y; v[6] = f1.z; v[7] = f1.w;
    }
    f16x8 hv;
#pragma unroll
    for (int j = 0; j < 8; j++) hv[j] = (_Float16)v[j];
    *(f16x8*)&lds_x[row * 256 + (((kq ^ (row & 7)) & 15) << 4)] = hv;
  }
  __syncthreads();

  f32x4 acc1[8][4];
#pragma unroll
  for (int ni = 0; ni < 8; ni++)
#pragma unroll
    for (int rt = 0; rt < 4; rt++) acc1[ni][rt] = (f32x4)(0.0f);

#pragma unroll
  for (int kt = 0; kt < 3; kt++) {
    f16x8 bx[4];
#pragma unroll
    for (int rt = 0; rt < 4; rt++) {
      int row = rt * 16 + l15;
      int kq = kt * 4 + quad;
      bx[rt] = *(const f16x8*)&lds_x[row * 256 + (((kq ^ (row & 7)) & 15) << 4)];
    }
#pragma unroll
    for (int ni = 0; ni < 8; ni++) {
      f16x8 aw = *(const f16x8*)&w1t[(ncol0 + ni * 16 + l15) * 96 + kt * 32 + quad * 8];
#pragma unroll
      for (int rt = 0; rt < 4; rt++) acc1[ni][rt] = MFMA16(aw, bx[rt], acc1[ni][rt]);
    }
  }

#pragma unroll
  for (int ni = 0; ni < 8; ni++) {
    float4 b1v = *(const float4*)&b1[ncol0 + ni * 16 + quad * 4];
    int kq2 = (ncol0 >> 3) + ni * 2 + (quad >> 1);
#pragma unroll
    for (int rt = 0; rt < 4; rt++) {
      int row = rt * 16 + l15;
      f16x4 hv;
      hv[0] = (_Float16)fmaxf(acc1[ni][rt][0] + b1v.x, 0.0f);
      hv[1] = (_Float16)fmaxf(acc1[ni][rt][1] + b1v.y, 0.0f);
      hv[2] = (_Float16)fmaxf(acc1[ni][rt][2] + b1v.z, 0.0f);
      hv[3] = (_Float16)fmaxf(acc1[ni][rt][3] + b1v.w, 0.0f);
      int swz = (kq2 & ~7) | ((kq2 & 7) ^ (row & 7));
      *(f16x4*)&lds_h[row * 1024 + (swz << 4) + ((quad & 1) << 3)] = hv;
    }
  }
  __syncthreads();

  f32x4 acc2[8][4];
#pragma unroll
  for (int ni = 0; ni < 8; ni++)
#pragma unroll
    for (int rt = 0; rt < 4; rt++) acc2[ni][rt] = (f32x4)(0.0f);

  // 1-deep software pipeline on the 8 w2t A-fragments
  f16x8 awp[8];
#pragma unroll
  for (int ni = 0; ni < 8; ni++)
    awp[ni] = *(const f16x8*)&w2t[(ncol0 + ni * 16 + l15) * 512 + quad * 8];

  for (int kt = 0; kt < 16; kt++) {
    f16x8 awn[8];
    if (kt < 15) {
#pragma unroll
      for (int ni = 0; ni < 8; ni++)
        awn[ni] = *(const f16x8*)&w2t[(ncol0 + ni * 16 + l15) * 512 +
                                      (kt + 1) * 32 + quad * 8];
    }
    f16x8 bh[4];
#pragma unroll
    for (int rt = 0; rt < 4; rt++) {
      int row = rt * 16 + l15;
      int kq = kt * 4 + quad;
      int swz = (kq & ~7) | ((kq & 7) ^ (row & 7));
      bh[rt] = *(const f16x8*)&lds_h[row * 1024 + (swz << 4)];
    }
#pragma unroll
    for (int ni = 0; ni < 8; ni++)
#pragma unroll
      for (int rt = 0; rt < 4; rt++)
        acc2[ni][rt] = MFMA16(awp[ni], bh[rt], acc2[ni][rt]);
    if (kt < 15) {
#pragma unroll
      for (int ni = 0; ni < 8; ni++) awp[ni] = awn[ni];
    }
  }

#pragma unroll
  for (int rt = 0; rt < 4; rt++) {
    int pr = R0 + rt * 16 + l15;
    int ch = pr / CHUNK_OUT, pos = pr - ch * CHUNK_OUT;
    bool valid = pos < CHUNK_IN;
    float s = 0.0f;
#pragma unroll
    for (int ni = 0; ni < 8; ni++) {
      float4 b2v = *(const float4*)&b2[ncol0 + ni * 16 + quad * 4];
      f16x4 ov;
      if (valid) {
        ov[0] = (_Float16)(acc2[ni][rt][0] + b2v.x);
        ov[1] = (_Float16)(acc2[ni][rt][1] + b2v.y);
        ov[2] = (_Float16)(acc2[ni][rt][2] + b2v.z);
        ov[3] = (_Float16)(acc2[ni][rt][3] + b2v.w);
#pragma unroll
        for (int r = 0; r < 4; r++) {
          float cv = (float)ov[r];
          s += cv * cv;
        }
      } else {
        ov[0] = (_Float16)0.0f; ov[1] = (_Float16)0.0f;
        ov[2] = (_Float16)0.0f; ov[3] = (_Float16)0.0f;
        s += 4.0f * 19.53125f;               // 1e4 / 512 per pad element
      }
      *(f16x4*)&out[pr * 512 + ncol0 + ni * 16 + quad * 4] = ov;
    }
    s += __shfl_xor(s, 16);
    s += __shfl_xor(s, 32);
    if (quad == 0) atomicAdd(&outsq[pr], s);
  }
}

// ---------------- fused distance + reductions (R5 frame + cross-tile prefetch)
// 1280 blocks x 512 threads at (512,2). id: xcd=id&7 (owns cols
// [xcd*12800,+12800)), by=(id>>3)&15 (64 q-rows), m=id>>7 -> g=xcd*10+m
// (1280 cols; wave w does tiles w, w+8, ... 5 tiles). 8-deep b-ring rolls
// across tiles: slots refilled at ks>=24 hold the NEXT tile's first 8 frags.
__global__ __launch_bounds__(512, 2) void dist_kernel(
    const _Float16* __restrict__ q, const _Float16* __restrict__ c,
    const float* __restrict__ qsq, const float* __restrict__ csq,
    const int* __restrict__ ypad, float* __restrict__ sumexp,
    float* __restrict__ lgts_part) {
  __shared__ __align__(16) char lds_q[65536];   // 64 rows x 64 units(16B) swz
  __shared__ __align__(16) char lds_ed[32768];  // 8 waves x 4KB (64x32 f16 swz)
  __shared__ float lds_qsq[64];

  const int t = threadIdx.x, w = t >> 6, l = t & 63;
  const int l31 = l & 31, half = l >> 5;
  const int l15 = l & 15, quad = (l >> 4) & 3;
  const int id = blockIdx.x;
  const int xcd = id & 7, by = (id >> 3) & 15, m = id >> 7;
  const int g = xcd * 10 + m;
  const int row0 = by * 64, chunk = g >> 2;   // 4 col-groups per 5120-chunk

  if (t < 64) lds_qsq[t] = qsq[row0 + t];

  // stage q rows [row0, row0+64) into swizzled LDS (coalesced, one-time)
#pragma unroll
  for (int it = 0; it < 8; it++) {
    int idx = it * 512 + t;
    int row = idx >> 6, u = idx & 63;
    f16x8 v = *(const f16x8*)&q[(size_t)(row0 + row) * 512 + u * 8];
    int swz = (u & ~7) | ((u & 7) ^ (row & 7));
    *(f16x8*)&lds_q[row * 1024 + (swz << 4)] = v;
  }
  __syncthreads();

  float sume0[16], sume1[16];
  f32x4 lacc[4];
#pragma unroll
  for (int reg = 0; reg < 16; reg++) { sume0[reg] = 0.0f; sume1[reg] = 0.0f; }
#pragma unroll
  for (int mt = 0; mt < 4; mt++) lacc[mt] = (f32x4)(0.0f);

  char* edbase = lds_ed + w * 4096;   // wave-private 64x32 f16 scratch (swz)

  // prefill ring with tile w's first 8 b-frags
  const size_t tstride = (size_t)8 * 32 * 512;   // elements between my tiles
  const _Float16* cb0 = c + ((size_t)(g * 1280 + w * 32 + l31) * 512) + half * 8;
  f16x8 br[8];
#pragma unroll
  for (int i = 0; i < 8; i++) br[i] = *(const f16x8*)(cb0 + i * 16);

#pragma unroll 1
  for (int i = 0; i < 5; i++) {
    int tile = w + 8 * i;
    int col0 = g * 1280 + tile * 32;
    const _Float16* cb = cb0 + (size_t)i * tstride;
    const _Float16* cbn = (i < 4) ? (cb + tstride) : cb;

    f32x16 acc0 = (f32x16)(0.0f), acc1 = (f32x16)(0.0f);

#pragma unroll
    for (int ks = 0; ks < 32; ks++) {
      f16x8 bc = br[ks & 7];
      // refill: ks<24 -> this tile's ks+8; ks>=24 -> NEXT tile's ks-24
      br[ks & 7] = (ks < 24) ? *(const f16x8*)(cb + (ks + 8) * 16)
                             : *(const f16x8*)(cbn + (ks - 24) * 16);
      int u = ks * 2 + half;
      int swz = (u & ~7) | ((u & 7) ^ (l31 & 7));   // (32+l31)&7 == l31&7
      f16x8 a0 = *(const f16x8*)&lds_q[l31 * 1024 + (swz << 4)];
      f16x8 a1 = *(const f16x8*)&lds_q[(32 + l31) * 1024 + (swz << 4)];
      acc0 = MFMA32(a0, bc, acc0);
      acc1 = MFMA32(a1, bc, acc1);
    }

    // epilogue: ed = exp(-dist); sume in regs; ed tile -> swizzled scratch
    float cs = csq[col0 + l31];
#pragma unroll
    for (int reg = 0; reg < 16; reg++) {
      int rr = (reg & 3) + 8 * (reg >> 2) + 4 * half;   // 0..31
      float ed0 = __expf(-sqrtf(fmaxf(lds_qsq[rr] + cs - 2.0f * acc0[reg], 0.0f)));
      float ed1 = __expf(-sqrtf(fmaxf(lds_qsq[32 + rr] + cs - 2.0f * acc1[reg], 0.0f)));
      sume0[reg] += __expf(ed0);     // pad cols: ed==0 -> adds exactly 1.0
      sume1[reg] += __expf(ed1);
      int r1 = 32 + rr;
      *(_Float16*)&edbase[rr * 64 + ((((l31 >> 3) ^ ((rr >> 1) & 3)) & 3) << 4) +
                          (l31 & 7) * 2] = (_Float16)ed0;
      *(_Float16*)&edbase[r1 * 64 + ((((l31 >> 3) ^ ((r1 >> 1) & 3)) & 3) << 4) +
                          (l31 & 7) * 2] = (_Float16)ed1;
    }

    // one-hot B-frag from ypad (classes in [0,10) -> lanes l15>=10 get zeros)
    int4 ya = *(const int4*)&ypad[col0 + quad * 8];
    int4 yb = *(const int4*)&ypad[col0 + quad * 8 + 4];
    f16x8 bf;
    bf[0] = (_Float16)(ya.x == l15 ? 1.0f : 0.0f);
    bf[1] = (_Float16)(ya.y == l15 ? 1.0f : 0.0f);
    bf[2] = (_Float16)(ya.z == l15 ? 1.0f : 0.0f);
    bf[3] = (_Float16)(ya.w == l15 ? 1.0f : 0.0f);
    bf[4] = (_Float16)(yb.x == l15 ? 1.0f : 0.0f);
    bf[5] = (_Float16)(yb.y == l15 ? 1.0f : 0.0f);
    bf[6] = (_Float16)(yb.z == l15 ? 1.0f : 0.0f);
    bf[7] = (_Float16)(yb.w == l15 ? 1.0f : 0.0f);

    // logits[row][class] += ed_tile @ onehot (same-wave DS ordering)
#pragma unroll
    for (int mt = 0; mt < 4; mt++) {
      int rowr = mt * 16 + l15;
      f16x8 af = *(const f16x8*)&edbase[rowr * 64 +
                                        (((quad ^ ((rowr >> 1) & 3)) & 3) << 4)];
      lacc[mt] = MFMA16(af, bf, lacc[mt]);
    }
  }

  // flush sumexp: reduce over the 32 col-lanes, 1 atomic per row
#pragma unroll
  for (int reg = 0; reg < 16; reg++) {
    float v0 = sume0[reg], v1 = sume1[reg];
    v0 += __shfl_xor(v0, 1);  v1 += __shfl_xor(v1, 1);
    v0 += __shfl_xor(v0, 2);  v1 += __shfl_xor(v1, 2);
    v0 += __shfl_xor(v0, 4);  v1 += __shfl_xor(v1, 4);
    v0 += __shfl_xor(v0, 8);  v1 += __shfl_xor(v1, 8);
    v0 += __shfl_xor(v0, 16); v1 += __shfl_xor(v1, 16);
    if (l31 == 0) {
      int rr = (reg & 3) + 8 * (reg >> 2) + 4 * half;
      atomicAdd(&sumexp[(row0 + rr) * 20 + chunk], v0);
      atomicAdd(&sumexp[(row0 + 32 + rr) * 20 + chunk], v1);
    }
  }

  // flush logits to this XCD's partial array (C-layout: col=class=l15)
  if (l15 < 10) {
    float* lp = lgts_part + (size_t)xcd * 10240 + row0 * 10;
#pragma unroll
    for (int mt = 0; mt < 4; mt++)
#pragma unroll
      for (int r = 0; r < 4; r++)
        atomicAdd(&lp[(mt * 16 + quad * 4 + r) * 10 + l15], lacc[mt][r]);
  }
}

// ---------------- finalize: out[i,k] = log(Σ_xcd lgts_part) - Σ_ch log(sumexp-120)
__global__ __launch_bounds__(256) void finalize_kernel(
    const float* __restrict__ lgts_part, const float* __restrict__ sumexp,
    float* __restrict__ out) {
  int i = blockIdx.x * 256 + threadIdx.x;
  if (i >= 1024) return;
  float lse = 0.0f;
#pragma unroll
  for (int ch = 0; ch < 20; ch++) lse += logf(sumexp[i * 20 + ch] - 120.0f);
#pragma unroll
  for (int k = 0; k < 10; k++) {
    float lg = 0.0f;
#pragma unroll
    for (int x = 0; x < 8; x++) lg += lgts_part[x * 10240 + i * 10 + k];
    out[i * 10 + k] = logf(lg) - lse;
  }
}

extern "C" void kernel_launch(void* const* d_in, const int* in_sizes, int n_in,
                              void* d_out, int out_size, void* d_ws, size_t ws_size,
                              hipStream_t stream) {
  const float* x_num = (const float*)d_in[0];
  const float* x_cat = (const float*)d_in[1];
  const float* cxn   = (const float*)d_in[2];
  const float* cxc   = (const float*)d_in[3];
  const int*   cy    = (const int*)d_in[4];
  const float* W1    = (const float*)d_in[5];
  const float* b1    = (const float*)d_in[6];
  const float* W2    = (const float*)d_in[7];
  const float* b2    = (const float*)d_in[8];
  float* out = (float*)d_out;

  char* ws = (char*)d_ws;
  _Float16* c    = (_Float16*)(ws + 0);           // 102400*512*2 = 104857600
  _Float16* qe   = (_Float16*)(ws + 104857600);   // 1024*512*2   = 1048576
  _Float16* w1t  = (_Float16*)(ws + 105906176);   // 512*96*2     = 98304
  _Float16* w2t  = (_Float16*)(ws + 106004480);   // 512*512*2    = 524288
  float*    csq  = (float*)(ws + 106528768);      // 102400*4     = 409600
  float*    qsq  = (float*)(ws + 106938368);      // 1024*4       = 4096
  float*    sume = (float*)(ws + 106942464);      // 1024*20*4    = 81920
  float*    lgtp = (float*)(ws + 107024384);      // 8*1024*10*4  = 327680
  int*      ypad = (int*)(ws + 107352064);        // 102400*4     = 409600

  prep_kernel<<<2420, 256, 0, stream>>>(W1, W2, cy, w1t, w2t, ypad, csq);
  encode_kernel<5000, 5120><<<1600, 256, 0, stream>>>(cxn, cxc, w1t, b1, w2t, b2, c, csq);
  encode_kernel<(1 << 20), (1 << 20)><<<16, 256, 0, stream>>>(x_num, x_cat, w1t, b1, w2t, b2, qe, qsq);
  dist_kernel<<<1280, 512, 0, stream>>>(qe, c, qsq, csq, ypad, sume, lgtp);
  finalize_kernel<<<4, 256, 0, stream>>>(lgtp, sume, out);
}

// Round 8
// 998.158 us; speedup vs baseline: 1.7890x; 1.0175x over previous
//
#include <hip/hip_runtime.h>
#include <hip/hip_bf16.h>

// ModernNCA fused pipeline for MI355X (gfx950). Round 8: k-outer/tile-inner.
//
// R7 lesson: cross-tile ring + persistent sume spilled (FETCH 1.3GB). R5
// (328us) is the clean frame; its flaws: 5x redundant q a-frag LDS reads
// (tile-outer loop) and only 2 MFMA32 per b-load batch.
// R8 dist: one 32-ks pass processes all 5 of the wave's tiles: per ks =
// 1 LDS a-read + 5 b-loads + 5 MFMA32. Wave = 32 rows x 5 tiles (acc 80
// AGPR); ring depth 3 (60 VGPR). 8 waves = 2 rowhalves x 4 colsets; group =
// 640 cols. LDS = 64KB q + 16KB ed = exactly 80KB -> 2 blocks/CU (16 waves,
// 4/SIMD) - the occupancy R6 failed to buy with registers.
//
// Padding: 5000->5120 per chunk; pad rows c=0, csq=1e4 -> d>=100 -> ed==0;
// each pad adds exp(0)=1 to chunk sumexp; finalize subtracts 120.

typedef _Float16 f16x8 __attribute__((ext_vector_type(8)));
typedef _Float16 f16x4 __attribute__((ext_vector_type(4)));
typedef float f32x4 __attribute__((ext_vector_type(4)));
typedef float f32x16 __attribute__((ext_vector_type(16)));

#define MFMA16(a, b, c) __builtin_amdgcn_mfma_f32_16x16x32_f16(a, b, c, 0, 0, 0)
#define MFMA32(a, b, c) __builtin_amdgcn_mfma_f32_32x32x16_f16(a, b, c, 0, 0, 0)

// ---------------- prep: W1t/W2t transpose+cast, padded y, zero accumulators
__global__ __launch_bounds__(256) void prep_kernel(
    const float* __restrict__ W1, const float* __restrict__ W2,
    const int* __restrict__ y, _Float16* __restrict__ w1t,
    _Float16* __restrict__ w2t, int* __restrict__ ypad,
    float* __restrict__ zero_base) {
  int idx = blockIdx.x * 256 + threadIdx.x;
  if (idx < 49152) {                       // W1 [96,512] -> W1t [512,96]
    int n = idx / 96, k = idx - n * 96;
    w1t[idx] = (_Float16)W1[k * 512 + n];
  } else if (idx < 311296) {               // W2 [512,512] -> W2t [512,512]
    int j = idx - 49152;
    int n = j / 512, k = j - n * 512;
    w2t[j] = (_Float16)W2[k * 512 + n];
  } else if (idx < 413696) {               // padded candidate_y
    int j = idx - 311296;
    int ch = j / 5120, pos = j - ch * 5120;
    ypad[j] = (pos < 5000) ? y[ch * 5000 + pos] : 0;
  } else if (idx < 619520) {
    // zero: csq(102400) qsq(1024) sumexp(20480) lgts_part(81920) = 205824 f32
    zero_base[idx - 413696] = 0.0f;
  }
}

// ---------------- fused 2-layer encoder: enc = relu(x@W1+b1)@W2 + b2
template <int CHUNK_IN, int CHUNK_OUT>
__global__ __launch_bounds__(256, 2) void encode_kernel(
    const float* __restrict__ xn, const float* __restrict__ xc,
    const _Float16* __restrict__ w1t, const float* __restrict__ b1,
    const _Float16* __restrict__ w2t, const float* __restrict__ b2,
    _Float16* __restrict__ out, float* __restrict__ outsq) {
  __shared__ __align__(16) char lds_x[16384];  // 64 rows x 16 units(16B) swz
  __shared__ __align__(16) char lds_h[65536];  // 64 rows x 64 units(16B) swz

  const int t = threadIdx.x;
  const int R0 = blockIdx.x * 64;
  const int w = t >> 6, l = t & 63;
  const int l15 = l & 15, quad = l >> 4;
  const int ncol0 = w * 128;

#pragma unroll
  for (int it = 0; it < 4; it++) {
    int idx = it * 256 + t;
    int row = idx >> 4, kq = idx & 15;
    int pr = R0 + row;
    int ch = pr / CHUNK_OUT, pos = pr - ch * CHUNK_OUT;
    float v[8] = {0, 0, 0, 0, 0, 0, 0, 0};
    if (pos < CHUNK_IN && kq < 12) {
      int orig = ch * CHUNK_IN + pos;
      float4 f0, f1;
      if (kq < 8) {
        f0 = *(const float4*)&xn[orig * 64 + kq * 8];
        f1 = *(const float4*)&xn[orig * 64 + kq * 8 + 4];
      } else {
        f0 = *(const float4*)&xc[orig * 32 + (kq - 8) * 8];
        f1 = *(const float4*)&xc[orig * 32 + (kq - 8) * 8 + 4];
      }
      v[0] = f0.x; v[1] = f0.y; v[2] = f0.z; v[3] = f0.w;
      v[4] = f1.x; v[5] = f1.y; v[6] = f1.z; v[7] = f1.w;
    }
    f16x8 hv;
#pragma unroll
    for (int j = 0; j < 8; j++) hv[j] = (_Float16)v[j];
    *(f16x8*)&lds_x[row * 256 + (((kq ^ (row & 7)) & 15) << 4)] = hv;
  }
  __syncthreads();

  f32x4 acc1[8][4];
#pragma unroll
  for (int ni = 0; ni < 8; ni++)
#pragma unroll
    for (int rt = 0; rt < 4; rt++) acc1[ni][rt] = (f32x4)(0.0f);

#pragma unroll
  for (int kt = 0; kt < 3; kt++) {
    f16x8 bx[4];
#pragma unroll
    for (int rt = 0; rt < 4; rt++) {
      int row = rt * 16 + l15;
      int kq = kt * 4 + quad;
      bx[rt] = *(const f16x8*)&lds_x[row * 256 + (((kq ^ (row & 7)) & 15) << 4)];
    }
#pragma unroll
    for (int ni = 0; ni < 8; ni++) {
      f16x8 aw = *(const f16x8*)&w1t[(ncol0 + ni * 16 + l15) * 96 + kt * 32 + quad * 8];
#pragma unroll
      for (int rt = 0; rt < 4; rt++) acc1[ni][rt] = MFMA16(aw, bx[rt], acc1[ni][rt]);
    }
  }

#pragma unroll
  for (int ni = 0; ni < 8; ni++) {
    float4 b1v = *(const float4*)&b1[ncol0 + ni * 16 + quad * 4];
    int kq2 = (ncol0 >> 3) + ni * 2 + (quad >> 1);
#pragma unroll
    for (int rt = 0; rt < 4; rt++) {
      int row = rt * 16 + l15;
      f16x4 hv;
      hv[0] = (_Float16)fmaxf(acc1[ni][rt][0] + b1v.x, 0.0f);
      hv[1] = (_Float16)fmaxf(acc1[ni][rt][1] + b1v.y, 0.0f);
      hv[2] = (_Float16)fmaxf(acc1[ni][rt][2] + b1v.z, 0.0f);
      hv[3] = (_Float16)fmaxf(acc1[ni][rt][3] + b1v.w, 0.0f);
      int swz = (kq2 & ~7) | ((kq2 & 7) ^ (row & 7));
      *(f16x4*)&lds_h[row * 1024 + (swz << 4) + ((quad & 1) << 3)] = hv;
    }
  }
  __syncthreads();

  f32x4 acc2[8][4];
#pragma unroll
  for (int ni = 0; ni < 8; ni++)
#pragma unroll
    for (int rt = 0; rt < 4; rt++) acc2[ni][rt] = (f32x4)(0.0f);

  f16x8 awp[8];
#pragma unroll
  for (int ni = 0; ni < 8; ni++)
    awp[ni] = *(const f16x8*)&w2t[(ncol0 + ni * 16 + l15) * 512 + quad * 8];

  for (int kt = 0; kt < 16; kt++) {
    f16x8 awn[8];
    if (kt < 15) {
#pragma unroll
      for (int ni = 0; ni < 8; ni++)
        awn[ni] = *(const f16x8*)&w2t[(ncol0 + ni * 16 + l15) * 512 +
                                      (kt + 1) * 32 + quad * 8];
    }
    f16x8 bh[4];
#pragma unroll
    for (int rt = 0; rt < 4; rt++) {
      int row = rt * 16 + l15;
      int kq = kt * 4 + quad;
      int swz = (kq & ~7) | ((kq & 7) ^ (row & 7));
      bh[rt] = *(const f16x8*)&lds_h[row * 1024 + (swz << 4)];
    }
#pragma unroll
    for (int ni = 0; ni < 8; ni++)
#pragma unroll
      for (int rt = 0; rt < 4; rt++)
        acc2[ni][rt] = MFMA16(awp[ni], bh[rt], acc2[ni][rt]);
    if (kt < 15) {
#pragma unroll
      for (int ni = 0; ni < 8; ni++) awp[ni] = awn[ni];
    }
  }

#pragma unroll
  for (int rt = 0; rt < 4; rt++) {
    int pr = R0 + rt * 16 + l15;
    int ch = pr / CHUNK_OUT, pos = pr - ch * CHUNK_OUT;
    bool valid = pos < CHUNK_IN;
    float s = 0.0f;
#pragma unroll
    for (int ni = 0; ni < 8; ni++) {
      float4 b2v = *(const float4*)&b2[ncol0 + ni * 16 + quad * 4];
      f16x4 ov;
      if (valid) {
        ov[0] = (_Float16)(acc2[ni][rt][0] + b2v.x);
        ov[1] = (_Float16)(acc2[ni][rt][1] + b2v.y);
        ov[2] = (_Float16)(acc2[ni][rt][2] + b2v.z);
        ov[3] = (_Float16)(acc2[ni][rt][3] + b2v.w);
#pragma unroll
        for (int r = 0; r < 4; r++) {
          float cv = (float)ov[r];
          s += cv * cv;
        }
      } else {
        ov[0] = (_Float16)0.0f; ov[1] = (_Float16)0.0f;
        ov[2] = (_Float16)0.0f; ov[3] = (_Float16)0.0f;
        s += 4.0f * 19.53125f;               // 1e4 / 512 per pad element
      }
      *(f16x4*)&out[pr * 512 + ncol0 + ni * 16 + quad * 4] = ov;
    }
    s += __shfl_xor(s, 16);
    s += __shfl_xor(s, 32);
    if (quad == 0) atomicAdd(&outsq[pr], s);
  }
}

// ---------------- fused distance + reductions (k-outer / tile-inner)
// 2560 blocks x 512 threads at (512,2). id: xcd=id&7 (owns cols
// [xcd*12800,+12800)), by=(id>>3)&15 (64 q-rows), m=id>>7 (0..19) ->
// g=xcd*20+m (640 cols = 20 tiles of 32). Wave w: rowhalf=w&1 (32 rows),
// colset=w>>1 -> 5 tiles {colset+4j}. One 32-ks pass: per ks 1 LDS a-read +
// 5 b-loads (ring depth 3) + 5 MFMA32. Then 5 tile-epilogues (exp + one-hot
// logit MFMA via wave-private ed scratch).
__global__ __launch_bounds__(512, 2) void dist_kernel(
    const _Float16* __restrict__ q, const _Float16* __restrict__ c,
    const float* __restrict__ qsq, const float* __restrict__ csq,
    const int* __restrict__ ypad, float* __restrict__ sumexp,
    float* __restrict__ lgts_part) {
  __shared__ __align__(16) char lds_q[65536];   // 64 rows x 64 units(16B) swz
  __shared__ __align__(16) char lds_ed[16384];  // 8 waves x 2KB (32x32 f16 swz)

  const int t = threadIdx.x, w = t >> 6, l = t & 63;
  const int l31 = l & 31, half = l >> 5;
  const int l15 = l & 15, quad = (l >> 4) & 3;
  const int id = blockIdx.x;
  const int xcd = id & 7, by = (id >> 3) & 15, m = id >> 7;   // m 0..19
  const int g = xcd * 20 + m;
  const int row0 = by * 64, chunk = g >> 3;   // 8 col-groups per 5120-chunk
  const int rowhalf = w & 1, colset = w >> 1;

  // stage q rows [row0, row0+64) into swizzled LDS (coalesced, one-time)
#pragma unroll
  for (int it = 0; it < 8; it++) {
    int idx = it * 512 + t;
    int row = idx >> 6, u = idx & 63;
    f16x8 v = *(const f16x8*)&q[(size_t)(row0 + row) * 512 + u * 8];
    int swz = (u & ~7) | ((u & 7) ^ (row & 7));
    *(f16x8*)&lds_q[row * 1024 + (swz << 4)] = v;
  }
  __syncthreads();

  // per-reg q row norms (rows row0 + 32*rowhalf + rr)
  float qsv[16];
#pragma unroll
  for (int reg = 0; reg < 16; reg++) {
    int rr = (reg & 3) + 8 * (reg >> 2) + 4 * half;
    qsv[reg] = qsq[row0 + 32 * rowhalf + rr];
  }

  float sume[16];
  f32x4 lacc[2];
#pragma unroll
  for (int reg = 0; reg < 16; reg++) sume[reg] = 0.0f;
  lacc[0] = (f32x4)(0.0f);
  lacc[1] = (f32x4)(0.0f);

  char* edbase = lds_ed + w * 2048;   // wave-private 32x32 f16 scratch (swz)

  // 5 tile base pointers (tiles colset + 4j), ring depth 3
  const _Float16* cb[5];
  const _Float16* base =
      c + (size_t)(g * 640 + colset * 32 + l31) * 512 + half * 8;
#pragma unroll
  for (int j = 0; j < 5; j++) cb[j] = base + (size_t)j * 65536;

  f16x8 br[5][3];
#pragma unroll
  for (int j = 0; j < 5; j++)
#pragma unroll
    for (int d = 0; d < 3; d++) br[j][d] = *(const f16x8*)(cb[j] + d * 16);

  f32x16 acc[5];
#pragma unroll
  for (int j = 0; j < 5; j++) acc[j] = (f32x16)(0.0f);

  const int arow = 32 * rowhalf + l31;
#pragma unroll
  for (int ks = 0; ks < 32; ks++) {
    int u = ks * 2 + half;
    int swz = (u & ~7) | ((u & 7) ^ (arow & 7));
    f16x8 a = *(const f16x8*)&lds_q[arow * 1024 + (swz << 4)];
#pragma unroll
    for (int j = 0; j < 5; j++) {
      f16x8 bc = br[j][ks % 3];
      if (ks < 29) br[j][ks % 3] = *(const f16x8*)(cb[j] + (ks + 3) * 16);
      acc[j] = MFMA32(a, bc, acc[j]);
    }
  }

  // 5 tile-epilogues
#pragma unroll 1
  for (int j = 0; j < 5; j++) {
    int col0 = g * 640 + (colset + 4 * j) * 32;
    float cs = csq[col0 + l31];
#pragma unroll
    for (int reg = 0; reg < 16; reg++) {
      int rr = (reg & 3) + 8 * (reg >> 2) + 4 * half;   // local row 0..31
      float dd = qsv[reg] + cs - 2.0f * acc[j][reg];
      float ed = __expf(-sqrtf(fmaxf(dd, 0.0f)));   // pad: d>=100 -> ed==0
      sume[reg] += __expf(ed);                       // pad adds exactly 1.0
      *(_Float16*)&edbase[rr * 64 + (((l31 >> 3) ^ (rr & 3)) << 4) +
                          (l31 & 7) * 2] = (_Float16)ed;
    }

    // one-hot B-frag from ypad (classes in [0,10) -> lanes l15>=10 get zeros)
    int4 ya = *(const int4*)&ypad[col0 + quad * 8];
    int4 yb = *(const int4*)&ypad[col0 + quad * 8 + 4];
    f16x8 bf;
    bf[0] = (_Float16)(ya.x == l15 ? 1.0f : 0.0f);
    bf[1] = (_Float16)(ya.y == l15 ? 1.0f : 0.0f);
    bf[2] = (_Float16)(ya.z == l15 ? 1.0f : 0.0f);
    bf[3] = (_Float16)(ya.w == l15 ? 1.0f : 0.0f);
    bf[4] = (_Float16)(yb.x == l15 ? 1.0f : 0.0f);
    bf[5] = (_Float16)(yb.y == l15 ? 1.0f : 0.0f);
    bf[6] = (_Float16)(yb.z == l15 ? 1.0f : 0.0f);
    bf[7] = (_Float16)(yb.w == l15 ? 1.0f : 0.0f);

    // logits[row][class] += ed_tile @ onehot (same-wave DS ordering)
#pragma unroll
    for (int mt = 0; mt < 2; mt++) {
      int rowr = mt * 16 + l15;
      f16x8 af = *(const f16x8*)&edbase[rowr * 64 +
                                        ((quad ^ (rowr & 3)) << 4)];
      lacc[mt] = MFMA16(af, bf, lacc[mt]);
    }
  }

  // flush sumexp: reduce over the 32 col-lanes (xor<=16 stays in half)
#pragma unroll
  for (int reg = 0; reg < 16; reg++) {
    float v = sume[reg];
    v += __shfl_xor(v, 1);
    v += __shfl_xor(v, 2);
    v += __shfl_xor(v, 4);
    v += __shfl_xor(v, 8);
    v += __shfl_xor(v, 16);
    if (l31 == 0) {
      int rr = (reg & 3) + 8 * (reg >> 2) + 4 * half;
      atomicAdd(&sumexp[(row0 + 32 * rowhalf + rr) * 20 + chunk], v);
    }
  }

  // flush logits to this XCD's partial array (C-layout: col=class=l15)
  if (l15 < 10) {
    float* lp = lgts_part + (size_t)xcd * 10240 + (row0 + 32 * rowhalf) * 10;
#pragma unroll
    for (int mt = 0; mt < 2; mt++)
#pragma unroll
      for (int r = 0; r < 4; r++)
        atomicAdd(&lp[(mt * 16 + quad * 4 + r) * 10 + l15], lacc[mt][r]);
  }
}

// ---------------- finalize: out[i,k] = log(Σ_xcd lgts_part) - Σ_ch log(sumexp-120)
__global__ __launch_bounds__(256) void finalize_kernel(
    const float* __restrict__ lgts_part, const float* __restrict__ sumexp,
    float* __restrict__ out) {
  int i = blockIdx.x * 256 + threadIdx.x;
  if (i >= 1024) return;
  float lse = 0.0f;
#pragma unroll
  for (int ch = 0; ch < 20; ch++) lse += logf(sumexp[i * 20 + ch] - 120.0f);
#pragma unroll
  for (int k = 0; k < 10; k++) {
    float lg = 0.0f;
#pragma unroll
    for (int x = 0; x < 8; x++) lg += lgts_part[x * 10240 + i * 10 + k];
    out[i * 10 + k] = logf(lg) - lse;
  }
}

extern "C" void kernel_launch(void* const* d_in, const int* in_sizes, int n_in,
                              void* d_out, int out_size, void* d_ws, size_t ws_size,
                              hipStream_t stream) {
  const float* x_num = (const float*)d_in[0];
  const float* x_cat = (const float*)d_in[1];
  const float* cxn   = (const float*)d_in[2];
  const float* cxc   = (const float*)d_in[3];
  const int*   cy    = (const int*)d_in[4];
  const float* W1    = (const float*)d_in[5];
  const float* b1    = (const float*)d_in[6];
  const float* W2    = (const float*)d_in[7];
  const float* b2    = (const float*)d_in[8];
  float* out = (float*)d_out;

  char* ws = (char*)d_ws;
  _Float16* c    = (_Float16*)(ws + 0);           // 102400*512*2 = 104857600
  _Float16* qe   = (_Float16*)(ws + 104857600);   // 1024*512*2   = 1048576
  _Float16* w1t  = (_Float16*)(ws + 105906176);   // 512*96*2     = 98304
  _Float16* w2t  = (_Float16*)(ws + 106004480);   // 512*512*2    = 524288
  float*    csq  = (float*)(ws + 106528768);      // 102400*4     = 409600
  float*    qsq  = (float*)(ws + 106938368);      // 1024*4       = 4096
  float*    sume = (float*)(ws + 106942464);      // 1024*20*4    = 81920
  float*    lgtp = (float*)(ws + 107024384);      // 8*1024*10*4  = 327680
  int*      ypad = (int*)(ws + 107352064);        // 102400*4     = 409600

  prep_kernel<<<2420, 256, 0, stream>>>(W1, W2, cy, w1t, w2t, ypad, csq);
  encode_kernel<5000, 5120><<<1600, 256, 0, stream>>>(cxn, cxc, w1t, b1, w2t, b2, c, csq);
  encode_kernel<(1 << 20), (1 << 20)><<<16, 256, 0, stream>>>(x_num, x_cat, w1t, b1, w2t, b2, qe, qsq);
  dist_kernel<<<2560, 512, 0, stream>>>(qe, c, qsq, csq, ypad, sume, lgtp);
  finalize_kernel<<<4, 256, 0, stream>>>(lgtp, sume, out);
}